// Round 7
// baseline (897.686 us; speedup 1.0000x reference)
//
#include <hip/hip_runtime.h>
#include <hip/hip_bf16.h>

// Problem constants (fixed by the reference: N=50000, E=400000, D=128, H=256, L=5)
#define NNODES 50000
#define MPAD 50048          // 391 * 128 (gemm row padding)
#define NEDGES 400000
#define DIM 128
#define HID 256
#define NLAYERS 5
#define BONDSZ 13
#define NCOMBO 60           // 5*6*2 bond-attr combinations
#define BN_EPS 1e-5f
#define NCHUNK 49           // ceil(50000/1024)
#define INVN (1.0f / 50000.0f)

typedef __bf16 bf16x8 __attribute__((ext_vector_type(8)));
typedef __bf16 bf16x4v __attribute__((ext_vector_type(4)));
typedef float f32x4 __attribute__((ext_vector_type(4)));

// Inline-asm 16B global load: cannot be sunk/rewritten by regalloc, dest
// stays live from issue to use, HW latency overlaps following code.
#define GLOAD16(dst, addr) \
    asm volatile("global_load_dwordx4 %0, %1, off" : "=v"(dst) : "v"(addr) : "memory")

// ===========================================================================
// CSR build (once per call — edge topology is layer-invariant)
// ===========================================================================
__global__ __launch_bounds__(256) void hist_kernel(
    const int* __restrict__ dst, int* __restrict__ deg)
{
    int e = blockIdx.x * 256 + threadIdx.x;
    if (e < NEDGES) atomicAdd(&deg[dst[e]], 1);
}

__global__ __launch_bounds__(256) void scan_sum(
    const int* __restrict__ deg, int* __restrict__ partial)
{
    __shared__ int red[256];
    int base = blockIdx.x * 1024;
    int s = 0;
    for (int i = threadIdx.x; i < 1024; i += 256) {
        int idx = base + i;
        if (idx < NNODES) s += deg[idx];
    }
    red[threadIdx.x] = s;
    __syncthreads();
    for (int off = 128; off > 0; off >>= 1) {
        if (threadIdx.x < off) red[threadIdx.x] += red[threadIdx.x + off];
        __syncthreads();
    }
    if (threadIdx.x == 0) partial[blockIdx.x] = red[0];
}

__global__ void scan_part(int* __restrict__ partial, int n, int* __restrict__ rowptr_last)
{
    if (threadIdx.x == 0) {
        int acc = 0;
        for (int i = 0; i < n; i++) { int v = partial[i]; partial[i] = acc; acc += v; }
        rowptr_last[0] = acc;
    }
}

__global__ __launch_bounds__(256) void scan_write(
    const int* __restrict__ deg, const int* __restrict__ partial,
    int* __restrict__ row_ptr)
{
    __shared__ int red[256];
    int base = blockIdx.x * 1024;
    int t = threadIdx.x;
    int v[4];
    int s = 0;
    #pragma unroll
    for (int j = 0; j < 4; j++) {
        int idx = base + t * 4 + j;
        v[j] = (idx < NNODES) ? deg[idx] : 0;
        s += v[j];
    }
    red[t] = s;
    __syncthreads();
    for (int off = 1; off < 256; off <<= 1) {
        int x = (t >= off) ? red[t - off] : 0;
        __syncthreads();
        red[t] += x;
        __syncthreads();
    }
    int ex = red[t] - s + partial[blockIdx.x];
    #pragma unroll
    for (int j = 0; j < 4; j++) {
        int idx = base + t * 4 + j;
        if (idx < NNODES) row_ptr[idx] = ex;
        ex += v[j];
    }
}

__global__ __launch_bounds__(256) void scatter_kernel(
    const int* __restrict__ src, const int* __restrict__ dst,
    const int* __restrict__ eattr, const int* __restrict__ row_ptr,
    int* __restrict__ cursor, int2* __restrict__ epack)
{
    int e = blockIdx.x * 256 + threadIdx.x;
    if (e >= NEDGES) return;
    int d = dst[e];
    int pos = row_ptr[d] + atomicAdd(&cursor[d], 1);
    int a0 = eattr[e * 3 + 0];
    int a1 = eattr[e * 3 + 1];
    int a2 = eattr[e * 3 + 2];
    epack[pos] = make_int2(src[e], a0 * 12 + a1 * 2 + a2);   // combo id 0..59
}

// ===========================================================================
// Weight pre-split (once): W -> transposed [n][k] bf16 hi/lo planes
// ===========================================================================
__global__ __launch_bounds__(256) void wsplit_kernel(
    const float* __restrict__ W1, const float* __restrict__ W2,
    __bf16* __restrict__ bt1h, __bf16* __restrict__ bt1l,
    __bf16* __restrict__ bt2h, __bf16* __restrict__ bt2l)
{
    int gid = blockIdx.x * 256 + threadIdx.x;
    const int total1 = NLAYERS * DIM * HID;
    if (gid < total1) {
        int n = gid % HID; int k = (gid / HID) % DIM; int l = gid / (DIM * HID);
        float w = W1[gid];
        __bf16 hi = (__bf16)w;
        int o = (l * HID + n) * DIM + k;
        bt1h[o] = hi; bt1l[o] = (__bf16)(w - (float)hi);
    } else {
        int g = gid - total1;
        if (g < NLAYERS * HID * DIM) {
            int n = g % DIM; int k = (g / DIM) % HID; int l = g / (HID * DIM);
            float w = W2[g];
            __bf16 hi = (__bf16)w;
            int o = (l * DIM + n) * HID + k;
            bt2h[o] = hi; bt2l[o] = (__bf16)(w - (float)hi);
        }
    }
}

// ===========================================================================
// Aggregation + GIN combine (CSR, zero atomics).  (round-4 structure:
//   4-deep edge pipeline; TRANS=1 gathers from bf16 plane y2b)
// ===========================================================================
template<int TRANS>
__global__ __launch_bounds__(1024) void agg_combine(
    const float* __restrict__ hin,
    const __bf16* __restrict__ hb,
    const int* __restrict__ row_ptr, const int2* __restrict__ epack,
    const float* __restrict__ bond,
    const float* __restrict__ epsv, int lidx,
    const float* __restrict__ csIn, const float* __restrict__ cqIn,
    const float* __restrict__ gamma, const float* __restrict__ beta,
    __bf16* __restrict__ zH, __bf16* __restrict__ zL,
    float* __restrict__ statsZero)
{
    __shared__ float T[BONDSZ * DIM];
    __shared__ float TC[NCOMBO * DIM];
    __shared__ float scs[DIM], shs[DIM];

    for (int i = threadIdx.x; i < BONDSZ * DIM; i += 1024) T[i] = bond[i];
    if (TRANS && threadIdx.x < DIM) {
        int c = threadIdx.x;
        float mu = csIn[c] * INVN;
        float var = cqIn[c] * INVN - mu * mu;
        float sv = gamma[c] * rsqrtf(var + BN_EPS);
        scs[c] = sv; shs[c] = beta[c] - mu * sv;
    }
    if (blockIdx.x == 0 && threadIdx.x < 768) statsZero[threadIdx.x] = 0.f;
    __syncthreads();
    // build combined table: TC[cb] = T[a0] + T[5+a1] + T[11+a2]
    for (int i = threadIdx.x; i < NCOMBO * DIM; i += 1024) {
        int cb = i >> 7, c = i & 127;
        int a0 = cb / 12, r = cb - a0 * 12;
        TC[i] = T[a0 * DIM + c] + T[(5 + (r >> 1)) * DIM + c] + T[(11 + (r & 1)) * DIM + c];
    }
    __syncthreads();

    const int wv = threadIdx.x >> 6;            // 0..15
    const int half = (threadIdx.x >> 5) & 1;
    const int li = threadIdx.x & 31;
    const int node = blockIdx.x * 32 + wv * 2 + half;
    if (node >= NNODES) return;
    const int f = li * 4;

    float4 sc4 = make_float4(1.f, 1.f, 1.f, 1.f);
    float4 sh4 = make_float4(0.f, 0.f, 0.f, 0.f);
    if (TRANS) { sc4 = *(const float4*)&scs[f]; sh4 = *(const float4*)&shs[f]; }

    float ax = 0.f, ay = 0.f, az = 0.f, aw = 0.f;
    const int s = row_ptr[node];
    const int e2 = row_ptr[node + 1];
    int i = s;
    // ---- 4-deep pipelined main loop
    for (; i + 3 < e2; i += 4) {
        int2 ev[4];
        ev[0] = epack[i];     ev[1] = epack[i + 1];
        ev[2] = epack[i + 2]; ev[3] = epack[i + 3];
        float4 gv[4], tv[4];
        #pragma unroll
        for (int u = 0; u < 4; u++) {
            if (TRANS) {
                bf16x4v gb = *(const bf16x4v*)&hb[(size_t)ev[u].x * DIM + f];
                gv[u] = make_float4((float)gb[0], (float)gb[1], (float)gb[2], (float)gb[3]);
            } else {
                gv[u] = *(const float4*)&hin[(size_t)ev[u].x * DIM + f];
            }
            tv[u] = *(const float4*)&TC[ev[u].y * DIM + f];
        }
        #pragma unroll
        for (int u = 0; u < 4; u++) {
            float4 g = gv[u], t = tv[u];
            if (TRANS) {
                g.x = fmaxf(g.x * sc4.x + sh4.x, 0.f); g.y = fmaxf(g.y * sc4.y + sh4.y, 0.f);
                g.z = fmaxf(g.z * sc4.z + sh4.z, 0.f); g.w = fmaxf(g.w * sc4.w + sh4.w, 0.f);
            }
            ax += fmaxf(g.x + t.x, 0.f);
            ay += fmaxf(g.y + t.y, 0.f);
            az += fmaxf(g.z + t.z, 0.f);
            aw += fmaxf(g.w + t.w, 0.f);
        }
    }
    // ---- tail (<=3 edges)
    for (; i < e2; i++) {
        int2 ev = epack[i];
        float4 g;
        if (TRANS) {
            bf16x4v gb = *(const bf16x4v*)&hb[(size_t)ev.x * DIM + f];
            g = make_float4((float)gb[0], (float)gb[1], (float)gb[2], (float)gb[3]);
        } else {
            g = *(const float4*)&hin[(size_t)ev.x * DIM + f];
        }
        float4 t = *(const float4*)&TC[ev.y * DIM + f];
        if (TRANS) {
            g.x = fmaxf(g.x * sc4.x + sh4.x, 0.f); g.y = fmaxf(g.y * sc4.y + sh4.y, 0.f);
            g.z = fmaxf(g.z * sc4.z + sh4.z, 0.f); g.w = fmaxf(g.w * sc4.w + sh4.w, 0.f);
        }
        ax += fmaxf(g.x + t.x, 0.f);
        ay += fmaxf(g.y + t.y, 0.f);
        az += fmaxf(g.z + t.z, 0.f);
        aw += fmaxf(g.w + t.w, 0.f);
    }
    // ---- self term (fp32 exact)
    float4 hv = *(const float4*)&hin[(size_t)node * DIM + f];
    if (TRANS) {
        hv.x = fmaxf(hv.x * sc4.x + sh4.x, 0.f); hv.y = fmaxf(hv.y * sc4.y + sh4.y, 0.f);
        hv.z = fmaxf(hv.z * sc4.z + sh4.z, 0.f); hv.w = fmaxf(hv.w * sc4.w + sh4.w, 0.f);
    }
    float ep = 1.0f + epsv[lidx];
    float z0 = ep * hv.x + ax, z1 = ep * hv.y + ay;
    float z2 = ep * hv.z + az, z3 = ep * hv.w + aw;
    __bf16 h0 = (__bf16)z0, h1 = (__bf16)z1, h2 = (__bf16)z2, h3 = (__bf16)z3;
    size_t o = (size_t)node * DIM + f;
    bf16x4v vh = {h0, h1, h2, h3};
    bf16x4v vl = {(__bf16)(z0 - (float)h0), (__bf16)(z1 - (float)h1),
                  (__bf16)(z2 - (float)h2), (__bf16)(z3 - (float)h3)};
    *(bf16x4v*)(zH + o) = vh;
    *(bf16x4v*)(zL + o) = vl;
}

// ===========================================================================
// Split-precision MFMA GEMM, register-resident A.
//   Round-7: LDS halved — only the B-HI plane is staged in LDS (swizzled);
//   B-LO is read per-kstep from global. The B panel is 64KB/layer, reused
//   by all row-blocks -> permanently L2-hot (~200cy, hidden by TLP).
//   Rationale: rounds 4-6 pinned gemm2 at ~45us / 2.2TB/s with only 2
//   blocks/CU resident (occupancy 22%, LDS 35KB) — each CU alternates
//   memory-phase / compute-phase with the HBM pipe idle during compute
//   (duty cycle ~35% == measured 2.2/6.3 TB/s). Halving LDS to ~19KB lifts
//   residency to 6-8 blocks/CU so block phases stagger and the pipe stays
//   busy. In-loop B-lo loads also keep memory demand continuous.
// ===========================================================================
template<int K, int NCOLS, int COLS, int NI, int TRANSFORM, int MINW>
__global__ __launch_bounds__(256, MINW) void gemm_as(
    const __bf16* __restrict__ AH, const __bf16* __restrict__ AL,
    const float* __restrict__ AF,
    const __bf16* __restrict__ BTH, const __bf16* __restrict__ BTL,
    const float* __restrict__ bias,
    const float* __restrict__ csIn, const float* __restrict__ cqIn,
    const float* __restrict__ gamma, const float* __restrict__ beta,
    float* __restrict__ outF, __bf16* __restrict__ outB,
    float* __restrict__ colsum, float* __restrict__ colsumsq)
{
    constexpr int KH  = (K > 128) ? 128 : K;   // staged K per round (16KB LDS)
    constexpr int NH  = K / KH;                // rounds
    constexpr int KCH = KH / 8;                // 16B chunks per col per round
    constexpr int NK  = K / 32;                // total ksteps
    constexpr int NKH = KH / 32;               // ksteps per round
    constexpr int NJ  = COLS / 16;             // col sub-blocks per wave
    constexpr int RB  = NI * 16 * 4;           // rows per block

    __shared__ __bf16 sBH[COLS * KH];          // B-hi only (B-lo from L2)
    __shared__ float redS[COLS], redQ[COLS];
    __shared__ float scs[TRANSFORM ? K : 1], shs[TRANSFORM ? K : 1];

    const int tid = threadIdx.x;
    const int lane = tid & 63;
    const int wv = tid >> 6;
    const int rowL = lane & 15;
    const int quad = lane >> 4;
    const int n0 = blockIdx.x * COLS;
    const int r0 = blockIdx.y * RB + wv * (NI * 16);

    // ---- A burst: ALL per-wave A loads issued via inline asm (held live).
    bf16x8 aH[NI][NK], aL[NI][NK];
    float4 pF[TRANSFORM ? NI : 1][TRANSFORM ? NK : 1][2];
    #pragma unroll
    for (int i = 0; i < NI; i++) {
        #pragma unroll
        for (int ks = 0; ks < NK; ks++) {
            size_t off = (size_t)(r0 + i * 16 + rowL) * K + ks * 32 + quad * 8;
            if constexpr (!TRANSFORM) {
                GLOAD16(aH[i][ks], AH + off);
                GLOAD16(aL[i][ks], AL + off);
            } else {
                GLOAD16(pF[i][ks][0], AF + off);
                GLOAD16(pF[i][ks][1], AF + off + 4);
            }
        }
    }

    if (tid < COLS) { redS[tid] = 0.f; redQ[tid] = 0.f; }
    if (TRANSFORM) {
        for (int c = tid; c < K; c += 256) {
            float mu = csIn[c] * INVN;
            float var = cqIn[c] * INVN - mu * mu;
            float sv = gamma[c] * rsqrtf(var + BN_EPS);
            scs[c] = sv; shs[c] = beta[c] - mu * sv;
        }
    }

    f32x4 acc[NI][NJ] = {};

    #pragma unroll
    for (int h = 0; h < NH; h++) {
        if (h > 0) __syncthreads();   // drain reads before restage
        // ---- stage this K-round of B-hi (swizzled chunk layout)
        #pragma unroll
        for (int it = 0; it < (COLS * KCH) / 256; it++) {
            int c = it * 256 + tid;
            int col = c / KCH, kq = c % KCH;
            int slot = col * KCH + (kq ^ (col & (KCH - 1)));
            size_t g = (size_t)(n0 + col) * K + h * KH + kq * 8;
            bf16x8 vh = *(const bf16x8*)(BTH + g);
            *(bf16x8*)(sBH + slot * 8) = vh;
        }
        __syncthreads();

        if (h == 0) {
            // drain the asm A-burst (overlapped with all of B staging);
            // sched_barrier stops reg-only uses from hoisting above the wait
            asm volatile("s_waitcnt vmcnt(0)" ::: "memory");
            __builtin_amdgcn_sched_barrier(0);
            // ---- one-time A transform (scs/shs valid after the barrier)
            if constexpr (TRANSFORM) {
                #pragma unroll
                for (int i = 0; i < NI; i++) {
                    #pragma unroll
                    for (int ks = 0; ks < NK; ks++) {
                        const int kb = ks * 32 + quad * 8;
                        float4 s0 = *(const float4*)&scs[kb];
                        float4 s1 = *(const float4*)&scs[kb + 4];
                        float4 t0 = *(const float4*)&shs[kb];
                        float4 t1 = *(const float4*)&shs[kb + 4];
                        float fv[8] = {pF[i][ks][0].x, pF[i][ks][0].y, pF[i][ks][0].z, pF[i][ks][0].w,
                                       pF[i][ks][1].x, pF[i][ks][1].y, pF[i][ks][1].z, pF[i][ks][1].w};
                        float sv[8] = {s0.x, s0.y, s0.z, s0.w, s1.x, s1.y, s1.z, s1.w};
                        float tv[8] = {t0.x, t0.y, t0.z, t0.w, t1.x, t1.y, t1.z, t1.w};
                        #pragma unroll
                        for (int e = 0; e < 8; e++) {
                            float v = fmaxf(fv[e] * sv[e] + tv[e], 0.f);
                            __bf16 hi = (__bf16)v;
                            aH[i][ks][e] = hi;
                            aL[i][ks][e] = (__bf16)(v - (float)hi);
                        }
                    }
                }
            }
        }

        // ---- K-loop for this round: B-hi from LDS, B-lo from L2
        #pragma unroll
        for (int kl = 0; kl < NKH; kl++) {
            const int ks = h * NKH + kl;
            const int kqr = kl * 4 + quad;
            // B-lo fragments straight from global (L2-resident weight panel)
            bf16x8 bl[NJ];
            #pragma unroll
            for (int j = 0; j < NJ; j++)
                bl[j] = *(const bf16x8*)(BTL + (size_t)(n0 + j * 16 + rowL) * K + ks * 32 + quad * 8);
            #pragma unroll
            for (int j = 0; j < NJ; j++) {
                int col = j * 16 + rowL;
                int slot = col * KCH + (kqr ^ (col & (KCH - 1)));
                bf16x8 bH = *(const bf16x8*)(sBH + slot * 8);
                #pragma unroll
                for (int i = 0; i < NI; i++) {
                    acc[i][j] = __builtin_amdgcn_mfma_f32_16x16x32_bf16(aH[i][ks], bH, acc[i][j], 0, 0, 0);
                    acc[i][j] = __builtin_amdgcn_mfma_f32_16x16x32_bf16(aL[i][ks], bH, acc[i][j], 0, 0, 0);
                    acc[i][j] = __builtin_amdgcn_mfma_f32_16x16x32_bf16(aH[i][ks], bl[j], acc[i][j], 0, 0, 0);
                }
            }
        }
    }

    // ---- epilogue: bias, fp32 store (+bf16 plane for TRANSFORM), col stats
    #pragma unroll
    for (int j = 0; j < NJ; j++) {
        const int colL = j * 16 + rowL;
        const float bb = bias[n0 + colL];
        float sj = 0.f, qj = 0.f;
        #pragma unroll
        for (int i = 0; i < NI; i++) {
            const int rbase = r0 + i * 16 + quad * 4;
            #pragma unroll
            for (int r = 0; r < 4; r++) {
                const int rr = rbase + r;
                if (rr < NNODES) {
                    float v = acc[i][j][r] + bb;
                    size_t oidx = (size_t)rr * NCOLS + n0 + colL;
                    outF[oidx] = v;
                    if (TRANSFORM) outB[oidx] = (__bf16)v;
                    sj += v;
                    qj += v * v;
                }
            }
        }
        sj += __shfl_xor(sj, 16); sj += __shfl_xor(sj, 32);
        qj += __shfl_xor(qj, 16); qj += __shfl_xor(qj, 32);
        if (quad == 0) {
            atomicAdd(&redS[colL], sj);
            atomicAdd(&redQ[colL], qj);
        }
    }
    __syncthreads();
    if (tid < COLS) {
        atomicAdd(&colsum[n0 + tid], redS[tid]);
        atomicAdd(&colsumsq[n0 + tid], redQ[tid]);
    }
}

// ===========================================================================
// Final outer BN (no relu), scale/shift computed inline from layer-4 stats.
// ===========================================================================
__global__ __launch_bounds__(256) void bn_out(
    const float* __restrict__ y2, const float* __restrict__ csIn,
    const float* __restrict__ cqIn, const float* __restrict__ gamma,
    const float* __restrict__ beta, float* __restrict__ out)
{
    __shared__ float scs[DIM], shs[DIM];
    if (threadIdx.x < DIM) {
        int c = threadIdx.x;
        float mu = csIn[c] * INVN;
        float var = cqIn[c] * INVN - mu * mu;
        float sv = gamma[c] * rsqrtf(var + BN_EPS);
        scs[c] = sv; shs[c] = beta[c] - mu * sv;
    }
    __syncthreads();
    int i = blockIdx.x * 256 + threadIdx.x;
    if (i >= NNODES * 32) return;
    int c = (i & 31) * 4;
    float4 v = *(const float4*)&y2[(size_t)i * 4];
    float4 s = *(const float4*)&scs[c];
    float4 t = *(const float4*)&shs[c];
    v.x = v.x * s.x + t.x;
    v.y = v.y * s.y + t.y;
    v.z = v.z * s.z + t.z;
    v.w = v.w * s.w + t.w;
    *(float4*)&out[(size_t)i * 4] = v;
}

extern "C" void kernel_launch(void* const* d_in, const int* in_sizes, int n_in,
                              void* d_out, int out_size, void* d_ws, size_t ws_size,
                              hipStream_t stream)
{
    const float* x    = (const float*)d_in[0];
    const int*   ei   = (const int*)d_in[1];
    const int*   ea   = (const int*)d_in[2];
    const float* W1   = (const float*)d_in[3];
    const float* b1   = (const float*)d_in[4];
    const float* g1   = (const float*)d_in[5];
    const float* bb1  = (const float*)d_in[6];
    const float* W2   = (const float*)d_in[7];
    const float* b2   = (const float*)d_in[8];
    const float* epsv = (const float*)d_in[9];
    const float* bond = (const float*)d_in[10];
    const float* g2   = (const float*)d_in[11];
    const float* bb2  = (const float*)d_in[12];
    float* out = (float*)d_out;

    const int* src = ei;
    const int* dstp = ei + NEDGES;

    // ---- workspace layout
    float* ws = (float*)d_ws;
    float* y2    = ws;                            // MPAD*DIM fp32
    float* y1F   = y2 + (size_t)MPAD * DIM;       // MPAD*HID fp32
    float* stats = y1F + (size_t)MPAD * HID;      // 2 sets x 768
    __bf16* zH   = (__bf16*)(stats + 2 * 768);
    __bf16* zL   = zH + (size_t)MPAD * DIM;
    __bf16* bt1h = zL + (size_t)MPAD * DIM;
    __bf16* bt1l = bt1h + (size_t)NLAYERS * DIM * HID;
    __bf16* bt2h = bt1l + (size_t)NLAYERS * DIM * HID;
    __bf16* bt2l = bt2h + (size_t)NLAYERS * HID * DIM;
    int* iws     = (int*)(bt2l + (size_t)NLAYERS * HID * DIM);
    int* deg     = iws;                  // 50000
    int* cursor  = deg + NNODES;         // 50000
    int* row_ptr = cursor + NNODES;      // 50001
    int* partial = row_ptr + NNODES + 1; // 64
    int2* epack  = (int2*)(partial + 64);// 400000 x int2
    __bf16* y2b  = (__bf16*)(((uintptr_t)(epack + NEDGES) + 15) & ~(uintptr_t)15);  // MPAD*DIM bf16

    // ---- build CSR (dst-sorted packed edge list) + split weights, once
    hipMemsetAsync(deg, 0, 2 * NNODES * sizeof(int), stream);
    hist_kernel<<<(NEDGES + 255) / 256, 256, 0, stream>>>(dstp, deg);
    scan_sum<<<NCHUNK, 256, 0, stream>>>(deg, partial);
    scan_part<<<1, 64, 0, stream>>>(partial, NCHUNK, row_ptr + NNODES);
    scan_write<<<NCHUNK, 256, 0, stream>>>(deg, partial, row_ptr);
    scatter_kernel<<<(NEDGES + 255) / 256, 256, 0, stream>>>(
        src, dstp, ea, row_ptr, cursor, epack);
    wsplit_kernel<<<(2 * NLAYERS * DIM * HID + 255) / 256, 256, 0, stream>>>(
        W1, W2, bt1h, bt1l, bt2h, bt2l);

    for (int l = 0; l < NLAYERS; l++) {
        const int p = l & 1;
        float* cs1 = stats + p * 768;
        float* cq1 = cs1 + HID;
        float* cs2 = cq1 + HID;
        float* cq2 = cs2 + DIM;
        float* statsZ = stats + p * 768;   // whole set, zeroed by agg block 0

        if (l == 0) {
            agg_combine<0><<<(NNODES + 31) / 32, 1024, 0, stream>>>(
                x, nullptr, row_ptr, epack, bond + (size_t)l * BONDSZ * DIM,
                epsv, l, nullptr, nullptr, nullptr, nullptr, zH, zL, statsZ);
        } else {
            const int pp = (l - 1) & 1;
            float* pcs2 = stats + pp * 768 + 2 * HID;
            float* pcq2 = pcs2 + DIM;
            agg_combine<1><<<(NNODES + 31) / 32, 1024, 0, stream>>>(
                y2, y2b, row_ptr, epack, bond + (size_t)l * BONDSZ * DIM,
                epsv, l, pcs2, pcq2, g2 + (size_t)(l - 1) * DIM,
                bb2 + (size_t)(l - 1) * DIM, zH, zL, statsZ);
        }

        // gemm1: [MPAD x 128] @ [128 x 256] -> y1F
        //   128-row blocks (NI=2), COLS=64, grid (4, 391), MINW=4, ~17KB LDS
        gemm_as<DIM, HID, 64, 2, 0, 4><<<dim3(HID / 64, MPAD / 128), 256, 0, stream>>>(
            zH, zL, nullptr,
            bt1h + (size_t)l * HID * DIM, bt1l + (size_t)l * HID * DIM,
            b1 + (size_t)l * HID, nullptr, nullptr, nullptr, nullptr,
            y1F, nullptr, cs1, cq1);

        // gemm2: [MPAD x 256] @ [256 x 128] -> y2 (+ y2b bf16 plane)
        //   64-row blocks (NI=1), COLS=64, grid (2, 782), MINW=2, ~19KB LDS
        gemm_as<HID, DIM, 64, 1, 1, 2><<<dim3(DIM / 64, MPAD / 64), 256, 0, stream>>>(
            nullptr, nullptr, y1F,
            bt2h + (size_t)l * DIM * HID, bt2l + (size_t)l * DIM * HID,
            b2 + (size_t)l * DIM, cs1, cq1, g1 + (size_t)l * HID,
            bb1 + (size_t)l * HID, y2, y2b, cs2, cq2);
    }

    // final outer BN (layer 4 -> parity 0), no relu
    {
        float* cs2 = stats + 0 * 768 + 2 * HID;
        float* cq2 = cs2 + DIM;
        bn_out<<<(NNODES * 32 + 255) / 256, 256, 0, stream>>>(
            y2, cs2, cq2, g2 + (size_t)4 * DIM, bb2 + (size_t)4 * DIM, out);
    }
}

// Round 8
// 812.163 us; speedup vs baseline: 1.1053x; 1.1053x over previous
//
#include <hip/hip_runtime.h>
#include <hip/hip_bf16.h>

// Problem constants (fixed by the reference: N=50000, E=400000, D=128, H=256, L=5)
#define NNODES 50000
#define MPAD 50048          // 391 * 128 (gemm row padding)
#define NEDGES 400000
#define DIM 128
#define HID 256
#define NLAYERS 5
#define BONDSZ 13
#define NCOMBO 60           // 5*6*2 bond-attr combinations
#define BN_EPS 1e-5f
#define NCHUNK 49           // ceil(50000/1024)
#define INVN (1.0f / 50000.0f)

typedef __bf16 bf16x8 __attribute__((ext_vector_type(8)));
typedef __bf16 bf16x4v __attribute__((ext_vector_type(4)));
typedef float f32x4 __attribute__((ext_vector_type(4)));

// Inline-asm 16B global load: cannot be sunk/rewritten by regalloc; dest
// stays live from issue to use. No "memory" clobber: sources are read-only
// arrays, and omitting it keeps the memory legalizer from inserting
// conservative vmcnt(0) drains between my counted waits.
#define GLOAD16(dst, addr) \
    asm volatile("global_load_dwordx4 %0, %1, off" : "=v"(dst) : "v"(addr))

// Counted vmcnt wait + scheduling fence (rule #18: reg-only consumers can
// be hoisted past an asm waitcnt unless a sched_barrier(0) pins it).
template<int N> __device__ __forceinline__ void vmwait() {
    if constexpr (N <= 0)       asm volatile("s_waitcnt vmcnt(0)"  ::: "memory");
    else if constexpr (N == 4)  asm volatile("s_waitcnt vmcnt(4)"  ::: "memory");
    else if constexpr (N == 6)  asm volatile("s_waitcnt vmcnt(6)"  ::: "memory");
    else if constexpr (N == 8)  asm volatile("s_waitcnt vmcnt(8)"  ::: "memory");
    else if constexpr (N == 12) asm volatile("s_waitcnt vmcnt(12)" ::: "memory");
    else static_assert(N == 0 || N == 4 || N == 6 || N == 8 || N == 12, "vmcnt case");
    __builtin_amdgcn_sched_barrier(0);
}

// ===========================================================================
// CSR build (once per call — edge topology is layer-invariant)
// ===========================================================================
__global__ __launch_bounds__(256) void hist_kernel(
    const int* __restrict__ dst, int* __restrict__ deg)
{
    int e = blockIdx.x * 256 + threadIdx.x;
    if (e < NEDGES) atomicAdd(&deg[dst[e]], 1);
}

__global__ __launch_bounds__(256) void scan_sum(
    const int* __restrict__ deg, int* __restrict__ partial)
{
    __shared__ int red[256];
    int base = blockIdx.x * 1024;
    int s = 0;
    for (int i = threadIdx.x; i < 1024; i += 256) {
        int idx = base + i;
        if (idx < NNODES) s += deg[idx];
    }
    red[threadIdx.x] = s;
    __syncthreads();
    for (int off = 128; off > 0; off >>= 1) {
        if (threadIdx.x < off) red[threadIdx.x] += red[threadIdx.x + off];
        __syncthreads();
    }
    if (threadIdx.x == 0) partial[blockIdx.x] = red[0];
}

__global__ void scan_part(int* __restrict__ partial, int n, int* __restrict__ rowptr_last)
{
    if (threadIdx.x == 0) {
        int acc = 0;
        for (int i = 0; i < n; i++) { int v = partial[i]; partial[i] = acc; acc += v; }
        rowptr_last[0] = acc;
    }
}

__global__ __launch_bounds__(256) void scan_write(
    const int* __restrict__ deg, const int* __restrict__ partial,
    int* __restrict__ row_ptr)
{
    __shared__ int red[256];
    int base = blockIdx.x * 1024;
    int t = threadIdx.x;
    int v[4];
    int s = 0;
    #pragma unroll
    for (int j = 0; j < 4; j++) {
        int idx = base + t * 4 + j;
        v[j] = (idx < NNODES) ? deg[idx] : 0;
        s += v[j];
    }
    red[t] = s;
    __syncthreads();
    for (int off = 1; off < 256; off <<= 1) {
        int x = (t >= off) ? red[t - off] : 0;
        __syncthreads();
        red[t] += x;
        __syncthreads();
    }
    int ex = red[t] - s + partial[blockIdx.x];
    #pragma unroll
    for (int j = 0; j < 4; j++) {
        int idx = base + t * 4 + j;
        if (idx < NNODES) row_ptr[idx] = ex;
        ex += v[j];
    }
}

__global__ __launch_bounds__(256) void scatter_kernel(
    const int* __restrict__ src, const int* __restrict__ dst,
    const int* __restrict__ eattr, const int* __restrict__ row_ptr,
    int* __restrict__ cursor, int2* __restrict__ epack)
{
    int e = blockIdx.x * 256 + threadIdx.x;
    if (e >= NEDGES) return;
    int d = dst[e];
    int pos = row_ptr[d] + atomicAdd(&cursor[d], 1);
    int a0 = eattr[e * 3 + 0];
    int a1 = eattr[e * 3 + 1];
    int a2 = eattr[e * 3 + 2];
    epack[pos] = make_int2(src[e], a0 * 12 + a1 * 2 + a2);   // combo id 0..59
}

// ===========================================================================
// Weight pre-split (once): W -> transposed [n][k] bf16 hi/lo planes
// ===========================================================================
__global__ __launch_bounds__(256) void wsplit_kernel(
    const float* __restrict__ W1, const float* __restrict__ W2,
    __bf16* __restrict__ bt1h, __bf16* __restrict__ bt1l,
    __bf16* __restrict__ bt2h, __bf16* __restrict__ bt2l)
{
    int gid = blockIdx.x * 256 + threadIdx.x;
    const int total1 = NLAYERS * DIM * HID;
    if (gid < total1) {
        int n = gid % HID; int k = (gid / HID) % DIM; int l = gid / (DIM * HID);
        float w = W1[gid];
        __bf16 hi = (__bf16)w;
        int o = (l * HID + n) * DIM + k;
        bt1h[o] = hi; bt1l[o] = (__bf16)(w - (float)hi);
    } else {
        int g = gid - total1;
        if (g < NLAYERS * HID * DIM) {
            int n = g % DIM; int k = (g / DIM) % HID; int l = g / (HID * DIM);
            float w = W2[g];
            __bf16 hi = (__bf16)w;
            int o = (l * DIM + n) * HID + k;
            bt2h[o] = hi; bt2l[o] = (__bf16)(w - (float)hi);
        }
    }
}

// ===========================================================================
// Aggregation + GIN combine (CSR, zero atomics).  (round-4 structure:
//   4-deep edge pipeline; TRANS=1 gathers from bf16 plane y2b)
// ===========================================================================
template<int TRANS>
__global__ __launch_bounds__(1024) void agg_combine(
    const float* __restrict__ hin,
    const __bf16* __restrict__ hb,
    const int* __restrict__ row_ptr, const int2* __restrict__ epack,
    const float* __restrict__ bond,
    const float* __restrict__ epsv, int lidx,
    const float* __restrict__ csIn, const float* __restrict__ cqIn,
    const float* __restrict__ gamma, const float* __restrict__ beta,
    __bf16* __restrict__ zH, __bf16* __restrict__ zL,
    float* __restrict__ statsZero)
{
    __shared__ float T[BONDSZ * DIM];
    __shared__ float TC[NCOMBO * DIM];
    __shared__ float scs[DIM], shs[DIM];

    for (int i = threadIdx.x; i < BONDSZ * DIM; i += 1024) T[i] = bond[i];
    if (TRANS && threadIdx.x < DIM) {
        int c = threadIdx.x;
        float mu = csIn[c] * INVN;
        float var = cqIn[c] * INVN - mu * mu;
        float sv = gamma[c] * rsqrtf(var + BN_EPS);
        scs[c] = sv; shs[c] = beta[c] - mu * sv;
    }
    if (blockIdx.x == 0 && threadIdx.x < 768) statsZero[threadIdx.x] = 0.f;
    __syncthreads();
    // build combined table: TC[cb] = T[a0] + T[5+a1] + T[11+a2]
    for (int i = threadIdx.x; i < NCOMBO * DIM; i += 1024) {
        int cb = i >> 7, c = i & 127;
        int a0 = cb / 12, r = cb - a0 * 12;
        TC[i] = T[a0 * DIM + c] + T[(5 + (r >> 1)) * DIM + c] + T[(11 + (r & 1)) * DIM + c];
    }
    __syncthreads();

    const int wv = threadIdx.x >> 6;            // 0..15
    const int half = (threadIdx.x >> 5) & 1;
    const int li = threadIdx.x & 31;
    const int node = blockIdx.x * 32 + wv * 2 + half;
    if (node >= NNODES) return;
    const int f = li * 4;

    float4 sc4 = make_float4(1.f, 1.f, 1.f, 1.f);
    float4 sh4 = make_float4(0.f, 0.f, 0.f, 0.f);
    if (TRANS) { sc4 = *(const float4*)&scs[f]; sh4 = *(const float4*)&shs[f]; }

    float ax = 0.f, ay = 0.f, az = 0.f, aw = 0.f;
    const int s = row_ptr[node];
    const int e2 = row_ptr[node + 1];
    int i = s;
    // ---- 4-deep pipelined main loop
    for (; i + 3 < e2; i += 4) {
        int2 ev[4];
        ev[0] = epack[i];     ev[1] = epack[i + 1];
        ev[2] = epack[i + 2]; ev[3] = epack[i + 3];
        float4 gv[4], tv[4];
        #pragma unroll
        for (int u = 0; u < 4; u++) {
            if (TRANS) {
                bf16x4v gb = *(const bf16x4v*)&hb[(size_t)ev[u].x * DIM + f];
                gv[u] = make_float4((float)gb[0], (float)gb[1], (float)gb[2], (float)gb[3]);
            } else {
                gv[u] = *(const float4*)&hin[(size_t)ev[u].x * DIM + f];
            }
            tv[u] = *(const float4*)&TC[ev[u].y * DIM + f];
        }
        #pragma unroll
        for (int u = 0; u < 4; u++) {
            float4 g = gv[u], t = tv[u];
            if (TRANS) {
                g.x = fmaxf(g.x * sc4.x + sh4.x, 0.f); g.y = fmaxf(g.y * sc4.y + sh4.y, 0.f);
                g.z = fmaxf(g.z * sc4.z + sh4.z, 0.f); g.w = fmaxf(g.w * sc4.w + sh4.w, 0.f);
            }
            ax += fmaxf(g.x + t.x, 0.f);
            ay += fmaxf(g.y + t.y, 0.f);
            az += fmaxf(g.z + t.z, 0.f);
            aw += fmaxf(g.w + t.w, 0.f);
        }
    }
    // ---- tail (<=3 edges)
    for (; i < e2; i++) {
        int2 ev = epack[i];
        float4 g;
        if (TRANS) {
            bf16x4v gb = *(const bf16x4v*)&hb[(size_t)ev.x * DIM + f];
            g = make_float4((float)gb[0], (float)gb[1], (float)gb[2], (float)gb[3]);
        } else {
            g = *(const float4*)&hin[(size_t)ev.x * DIM + f];
        }
        float4 t = *(const float4*)&TC[ev.y * DIM + f];
        if (TRANS) {
            g.x = fmaxf(g.x * sc4.x + sh4.x, 0.f); g.y = fmaxf(g.y * sc4.y + sh4.y, 0.f);
            g.z = fmaxf(g.z * sc4.z + sh4.z, 0.f); g.w = fmaxf(g.w * sc4.w + sh4.w, 0.f);
        }
        ax += fmaxf(g.x + t.x, 0.f);
        ay += fmaxf(g.y + t.y, 0.f);
        az += fmaxf(g.z + t.z, 0.f);
        aw += fmaxf(g.w + t.w, 0.f);
    }
    // ---- self term (fp32 exact)
    float4 hv = *(const float4*)&hin[(size_t)node * DIM + f];
    if (TRANS) {
        hv.x = fmaxf(hv.x * sc4.x + sh4.x, 0.f); hv.y = fmaxf(hv.y * sc4.y + sh4.y, 0.f);
        hv.z = fmaxf(hv.z * sc4.z + sh4.z, 0.f); hv.w = fmaxf(hv.w * sc4.w + sh4.w, 0.f);
    }
    float ep = 1.0f + epsv[lidx];
    float z0 = ep * hv.x + ax, z1 = ep * hv.y + ay;
    float z2 = ep * hv.z + az, z3 = ep * hv.w + aw;
    __bf16 h0 = (__bf16)z0, h1 = (__bf16)z1, h2 = (__bf16)z2, h3 = (__bf16)z3;
    size_t o = (size_t)node * DIM + f;
    bf16x4v vh = {h0, h1, h2, h3};
    bf16x4v vl = {(__bf16)(z0 - (float)h0), (__bf16)(z1 - (float)h1),
                  (__bf16)(z2 - (float)h2), (__bf16)(z3 - (float)h3)};
    *(bf16x4v*)(zH + o) = vh;
    *(bf16x4v*)(zL + o) = vl;
}

// ===========================================================================
// Split-precision MFMA GEMM — counted-vmcnt software pipeline (T4).
//   Round-8 model: rounds 4-6 proved the burst/drain structure phase-locks
//   the CU (all waves hold 0 outstanding loads during compute/epilogue ->
//   measured 2.2 TB/s = 35% duty). Fix: NEVER drain vmcnt to 0 in the main
//   loop. All K-loop VMEM is inline-asm GLOAD16; per kstep a counted
//   s_waitcnt vmcnt(L*(D-1)) completes only the oldest kstep's loads while
//   D-1 ksteps stay in flight. Zero compiler VMEM between the stage
//   barrier and the epilogue, so the counts are exact.
//   STAGEB2=1 (gemm1): both B planes in LDS (32KB), pipeline A only (L=4,D=2).
//   STAGEB2=0 (gemm2): B-hi in LDS (32KB, single round, no restage barrier),
//   pipeline A + B-lo (L=6, D=3); B-lo is L2-hot (panel shared by 782 blocks)
//   and prefetched D ksteps ahead (unlike round-7's demand loads).
//   TRANSFORM=1: A fp32, BN+ReLU+split per kstep at consume time.
// ===========================================================================
template<int K, int NCOLS, int COLS, int NI, int TRANSFORM, int STAGEB2, int D>
__global__ __launch_bounds__(256, 2) void gemm_pl(
    const __bf16* __restrict__ AH, const __bf16* __restrict__ AL,
    const float* __restrict__ AF,
    const __bf16* __restrict__ BTH, const __bf16* __restrict__ BTL,
    const float* __restrict__ bias,
    const float* __restrict__ csIn, const float* __restrict__ cqIn,
    const float* __restrict__ gamma, const float* __restrict__ beta,
    float* __restrict__ outF, __bf16* __restrict__ outB,
    float* __restrict__ colsum, float* __restrict__ colsumsq)
{
    constexpr int KC = K / 8;                  // 16B chunks per col
    constexpr int NK = K / 32;                 // ksteps
    constexpr int NJ = COLS / 16;              // col sub-blocks per wave
    constexpr int RB = NI * 64;                // rows per block (4 waves)
    constexpr int L  = NI * 2 + (STAGEB2 ? 0 : NJ);   // asm loads per kstep
    static_assert(!TRANSFORM || NI == 1, "TRANSFORM requires NI==1");

    __shared__ __bf16 sBH[COLS * K];
    __shared__ __bf16 sBL[STAGEB2 ? COLS * K : 1];
    __shared__ float redS[COLS], redQ[COLS];
    __shared__ float scs[TRANSFORM ? K : 1], shs[TRANSFORM ? K : 1];

    const int tid = threadIdx.x;
    const int lane = tid & 63;
    const int wv = tid >> 6;
    const int rowL = lane & 15;
    const int quad = lane >> 4;
    const int n0 = blockIdx.x * COLS;
    const int r0 = blockIdx.y * RB + wv * (NI * 16);

    if (tid < COLS) { redS[tid] = 0.f; redQ[tid] = 0.f; }
    if (TRANSFORM) {
        for (int c = tid; c < K; c += 256) {
            float mu = csIn[c] * INVN;
            float var = cqIn[c] * INVN - mu * mu;
            float sv = gamma[c] * rsqrtf(var + BN_EPS);
            scs[c] = sv; shs[c] = beta[c] - mu * sv;
        }
    }

    // ---- stage B (C++ loads; ALL compiler VMEM confined before the barrier)
    #pragma unroll
    for (int it = 0; it < (COLS * KC) / 256; it++) {
        int c = it * 256 + tid;
        int col = c / KC, kq = c % KC;
        int slot = col * KC + (kq ^ (col & (KC - 1)));
        size_t g = (size_t)(n0 + col) * K + kq * 8;
        *(bf16x8*)(sBH + slot * 8) = *(const bf16x8*)(BTH + g);
        if constexpr (STAGEB2)
            *(bf16x8*)(sBL + slot * 8) = *(const bf16x8*)(BTL + g);
    }
    __syncthreads();   // compiler drains its stage loads here; vmcnt==0 now

    // ---- pipeline registers (ring of depth D, all indices compile-time)
    bf16x8 pH[D][NI], pL[D][NI];               // TRANSFORM=0 A
    float4 pF[D][2];                           // TRANSFORM=1 A (NI==1)
    bf16x8 bl[D][NJ];                          // B-lo (STAGEB2=0)
    f32x4 acc[NI][NJ] = {};

#define ISSUE(ksv) do {                                                         \
    constexpr int _ks = (ksv); constexpr int _b = _ks % D;                      \
    _Pragma("unroll")                                                           \
    for (int i = 0; i < NI; i++) {                                              \
        size_t o = (size_t)(r0 + i * 16 + rowL) * K + _ks * 32 + quad * 8;      \
        if constexpr (!TRANSFORM) {                                             \
            GLOAD16(pH[_b][i], AH + o);                                         \
            GLOAD16(pL[_b][i], AL + o);                                         \
        } else {                                                                \
            GLOAD16(pF[_b][0], AF + o);                                         \
            GLOAD16(pF[_b][1], AF + o + 4);                                     \
        }                                                                       \
    }                                                                           \
    if constexpr (!STAGEB2) {                                                   \
        _Pragma("unroll")                                                       \
        for (int j = 0; j < NJ; j++)                                            \
            GLOAD16(bl[_b][j],                                                  \
                    BTL + (size_t)(n0 + j * 16 + rowL) * K + _ks * 32 + quad * 8); \
    }                                                                           \
} while (0)

    // ---- prologue: fill the pipeline
    ISSUE(0);
    if constexpr (D > 1) ISSUE(1);
    if constexpr (D > 2) ISSUE(2);

#define KSTEP(ksv) do { if constexpr ((ksv) < NK) {                             \
    constexpr int ks = (ksv); constexpr int buf = ks % D;                       \
    constexpr int rem = ((ks + D < NK) ? D : NK - ks) - 1;                      \
    vmwait<L * rem>();                                                          \
    bf16x8 aH8[NI], aL8[NI];                                                    \
    if constexpr (!TRANSFORM) {                                                 \
        _Pragma("unroll")                                                       \
        for (int i = 0; i < NI; i++) { aH8[i] = pH[buf][i]; aL8[i] = pL[buf][i]; } \
    } else {                                                                    \
        const int kb = ks * 32 + quad * 8;                                      \
        float4 s0 = *(const float4*)&scs[kb];                                   \
        float4 s1 = *(const float4*)&scs[kb + 4];                               \
        float4 t0 = *(const float4*)&shs[kb];                                   \
        float4 t1 = *(const float4*)&shs[kb + 4];                               \
        float fv[8] = {pF[buf][0].x, pF[buf][0].y, pF[buf][0].z, pF[buf][0].w,  \
                       pF[buf][1].x, pF[buf][1].y, pF[buf][1].z, pF[buf][1].w}; \
        float sv[8] = {s0.x, s0.y, s0.z, s0.w, s1.x, s1.y, s1.z, s1.w};         \
        float tv[8] = {t0.x, t0.y, t0.z, t0.w, t1.x, t1.y, t1.z, t1.w};         \
        _Pragma("unroll")                                                       \
        for (int e = 0; e < 8; e++) {                                           \
            float v = fmaxf(fv[e] * sv[e] + tv[e], 0.f);                        \
            __bf16 hi = (__bf16)v;                                              \
            aH8[0][e] = hi;                                                     \
            aL8[0][e] = (__bf16)(v - (float)hi);                                \
        }                                                                       \
    }                                                                           \
    const int kqr = ks * 4 + quad;                                              \
    _Pragma("unroll")                                                           \
    for (int j = 0; j < NJ; j++) {                                              \
        int col = j * 16 + rowL;                                                \
        int slot = col * KC + (kqr ^ (col & (KC - 1)));                         \
        bf16x8 bH = *(const bf16x8*)(sBH + slot * 8);                           \
        bf16x8 bLf;                                                             \
        if constexpr (STAGEB2) bLf = *(const bf16x8*)(sBL + slot * 8);          \
        else                   bLf = bl[buf][j];                                \
        _Pragma("unroll")                                                       \
        for (int i = 0; i < NI; i++) {                                          \
            acc[i][j] = __builtin_amdgcn_mfma_f32_16x16x32_bf16(aH8[i], bH, acc[i][j], 0, 0, 0); \
            acc[i][j] = __builtin_amdgcn_mfma_f32_16x16x32_bf16(aL8[i], bH, acc[i][j], 0, 0, 0); \
            acc[i][j] = __builtin_amdgcn_mfma_f32_16x16x32_bf16(aH8[i], bLf, acc[i][j], 0, 0, 0); \
        }                                                                       \
    }                                                                           \
    if constexpr (ks + D < NK) ISSUE(ks + D);                                   \
} } while (0)

    KSTEP(0); KSTEP(1); KSTEP(2); KSTEP(3);
    KSTEP(4); KSTEP(5); KSTEP(6); KSTEP(7);

#undef KSTEP
#undef ISSUE

    // ---- epilogue: bias, fp32 store (+bf16 plane for TRANSFORM), col stats
    #pragma unroll
    for (int j = 0; j < NJ; j++) {
        const int colL = j * 16 + rowL;
        const float bb = bias[n0 + colL];
        float sj = 0.f, qj = 0.f;
        #pragma unroll
        for (int i = 0; i < NI; i++) {
            const int rbase = r0 + i * 16 + quad * 4;
            #pragma unroll
            for (int r = 0; r < 4; r++) {
                const int rr = rbase + r;
                if (rr < NNODES) {
                    float v = acc[i][j][r] + bb;
                    size_t oidx = (size_t)rr * NCOLS + n0 + colL;
                    outF[oidx] = v;
                    if (TRANSFORM) outB[oidx] = (__bf16)v;
                    sj += v;
                    qj += v * v;
                }
            }
        }
        sj += __shfl_xor(sj, 16); sj += __shfl_xor(sj, 32);
        qj += __shfl_xor(qj, 16); qj += __shfl_xor(qj, 32);
        if (quad == 0) {
            atomicAdd(&redS[colL], sj);
            atomicAdd(&redQ[colL], qj);
        }
    }
    __syncthreads();
    if (tid < COLS) {
        atomicAdd(&colsum[n0 + tid], redS[tid]);
        atomicAdd(&colsumsq[n0 + tid], redQ[tid]);
    }
}

// ===========================================================================
// Final outer BN (no relu), scale/shift computed inline from layer-4 stats.
// ===========================================================================
__global__ __launch_bounds__(256) void bn_out(
    const float* __restrict__ y2, const float* __restrict__ csIn,
    const float* __restrict__ cqIn, const float* __restrict__ gamma,
    const float* __restrict__ beta, float* __restrict__ out)
{
    __shared__ float scs[DIM], shs[DIM];
    if (threadIdx.x < DIM) {
        int c = threadIdx.x;
        float mu = csIn[c] * INVN;
        float var = cqIn[c] * INVN - mu * mu;
        float sv = gamma[c] * rsqrtf(var + BN_EPS);
        scs[c] = sv; shs[c] = beta[c] - mu * sv;
    }
    __syncthreads();
    int i = blockIdx.x * 256 + threadIdx.x;
    if (i >= NNODES * 32) return;
    int c = (i & 31) * 4;
    float4 v = *(const float4*)&y2[(size_t)i * 4];
    float4 s = *(const float4*)&scs[c];
    float4 t = *(const float4*)&shs[c];
    v.x = v.x * s.x + t.x;
    v.y = v.y * s.y + t.y;
    v.z = v.z * s.z + t.z;
    v.w = v.w * s.w + t.w;
    *(float4*)&out[(size_t)i * 4] = v;
}

extern "C" void kernel_launch(void* const* d_in, const int* in_sizes, int n_in,
                              void* d_out, int out_size, void* d_ws, size_t ws_size,
                              hipStream_t stream)
{
    const float* x    = (const float*)d_in[0];
    const int*   ei   = (const int*)d_in[1];
    const int*   ea   = (const int*)d_in[2];
    const float* W1   = (const float*)d_in[3];
    const float* b1   = (const float*)d_in[4];
    const float* g1   = (const float*)d_in[5];
    const float* bb1  = (const float*)d_in[6];
    const float* W2   = (const float*)d_in[7];
    const float* b2   = (const float*)d_in[8];
    const float* epsv = (const float*)d_in[9];
    const float* bond = (const float*)d_in[10];
    const float* g2   = (const float*)d_in[11];
    const float* bb2  = (const float*)d_in[12];
    float* out = (float*)d_out;

    const int* src = ei;
    const int* dstp = ei + NEDGES;

    // ---- workspace layout
    float* ws = (float*)d_ws;
    float* y2    = ws;                            // MPAD*DIM fp32
    float* y1F   = y2 + (size_t)MPAD * DIM;       // MPAD*HID fp32
    float* stats = y1F + (size_t)MPAD * HID;      // 2 sets x 768
    __bf16* zH   = (__bf16*)(stats + 2 * 768);
    __bf16* zL   = zH + (size_t)MPAD * DIM;
    __bf16* bt1h = zL + (size_t)MPAD * DIM;
    __bf16* bt1l = bt1h + (size_t)NLAYERS * DIM * HID;
    __bf16* bt2h = bt1l + (size_t)NLAYERS * DIM * HID;
    __bf16* bt2l = bt2h + (size_t)NLAYERS * HID * DIM;
    int* iws     = (int*)(bt2l + (size_t)NLAYERS * HID * DIM);
    int* deg     = iws;                  // 50000
    int* cursor  = deg + NNODES;         // 50000
    int* row_ptr = cursor + NNODES;      // 50001
    int* partial = row_ptr + NNODES + 1; // 64
    int2* epack  = (int2*)(partial + 64);// 400000 x int2
    __bf16* y2b  = (__bf16*)(((uintptr_t)(epack + NEDGES) + 15) & ~(uintptr_t)15);  // MPAD*DIM bf16

    // ---- build CSR (dst-sorted packed edge list) + split weights, once
    hipMemsetAsync(deg, 0, 2 * NNODES * sizeof(int), stream);
    hist_kernel<<<(NEDGES + 255) / 256, 256, 0, stream>>>(dstp, deg);
    scan_sum<<<NCHUNK, 256, 0, stream>>>(deg, partial);
    scan_part<<<1, 64, 0, stream>>>(partial, NCHUNK, row_ptr + NNODES);
    scan_write<<<NCHUNK, 256, 0, stream>>>(deg, partial, row_ptr);
    scatter_kernel<<<(NEDGES + 255) / 256, 256, 0, stream>>>(
        src, dstp, ea, row_ptr, cursor, epack);
    wsplit_kernel<<<(2 * NLAYERS * DIM * HID + 255) / 256, 256, 0, stream>>>(
        W1, W2, bt1h, bt1l, bt2h, bt2l);

    for (int l = 0; l < NLAYERS; l++) {
        const int p = l & 1;
        float* cs1 = stats + p * 768;
        float* cq1 = cs1 + HID;
        float* cs2 = cq1 + HID;
        float* cq2 = cs2 + DIM;
        float* statsZ = stats + p * 768;   // whole set, zeroed by agg block 0

        if (l == 0) {
            agg_combine<0><<<(NNODES + 31) / 32, 1024, 0, stream>>>(
                x, nullptr, row_ptr, epack, bond + (size_t)l * BONDSZ * DIM,
                epsv, l, nullptr, nullptr, nullptr, nullptr, zH, zL, statsZ);
        } else {
            const int pp = (l - 1) & 1;
            float* pcs2 = stats + pp * 768 + 2 * HID;
            float* pcq2 = pcs2 + DIM;
            agg_combine<1><<<(NNODES + 31) / 32, 1024, 0, stream>>>(
                y2, y2b, row_ptr, epack, bond + (size_t)l * BONDSZ * DIM,
                epsv, l, pcs2, pcq2, g2 + (size_t)(l - 1) * DIM,
                bb2 + (size_t)(l - 1) * DIM, zH, zL, statsZ);
        }

        // gemm1: [MPAD x 128] @ [128 x 256] -> y1F
        //   NI=2 (128-row blocks), COLS=64, grid (4,391); both B planes in
        //   LDS (32KB); A pipelined depth-2, counted vmcnt(4)
        gemm_pl<DIM, HID, 64, 2, 0, 1, 2><<<dim3(HID / 64, MPAD / 128), 256, 0, stream>>>(
            zH, zL, nullptr,
            bt1h + (size_t)l * HID * DIM, bt1l + (size_t)l * HID * DIM,
            b1 + (size_t)l * HID, nullptr, nullptr, nullptr, nullptr,
            y1F, nullptr, cs1, cq1);

        // gemm2: [MPAD x 256] @ [256 x 128] -> y2 (+ y2b bf16 plane)
        //   NI=1 (64-row blocks), COLS=64, grid (2,782); B-hi in LDS (32KB,
        //   single round); A + B-lo pipelined depth-3, counted vmcnt(12)/6/0
        gemm_pl<HID, DIM, 64, 1, 1, 0, 3><<<dim3(DIM / 64, MPAD / 64), 256, 0, stream>>>(
            nullptr, nullptr, y1F,
            bt2h + (size_t)l * DIM * HID, bt2l + (size_t)l * DIM * HID,
            b2 + (size_t)l * DIM, cs1, cq1, g1 + (size_t)l * HID,
            bb1 + (size_t)l * HID, y2, y2b, cs2, cq2);
    }

    // final outer BN (layer 4 -> parity 0), no relu
    {
        float* cs2 = stats + 0 * 768 + 2 * HID;
        float* cq2 = cs2 + DIM;
        bn_out<<<(NNODES * 32 + 255) / 256, 256, 0, stream>>>(
            y2, cs2, cq2, g2 + (size_t)4 * DIM, bb2 + (size_t)4 * DIM, out);
    }
}

// Round 9
// 706.516 us; speedup vs baseline: 1.2706x; 1.1495x over previous
//
#include <hip/hip_runtime.h>
#include <hip/hip_bf16.h>

// Problem constants (fixed by the reference: N=50000, E=400000, D=128, H=256, L=5)
#define NNODES 50000
#define MPAD 50048          // 391 * 128 (gemm row padding)
#define NEDGES 400000
#define DIM 128
#define HID 256
#define NLAYERS 5
#define BONDSZ 13
#define NCOMBO 60           // 5*6*2 bond-attr combinations
#define BN_EPS 1e-5f
#define NCHUNK 49           // ceil(50000/1024)
#define INVN (1.0f / 50000.0f)

typedef __bf16 bf16x8 __attribute__((ext_vector_type(8)));
typedef __bf16 bf16x4v __attribute__((ext_vector_type(4)));
typedef float f32x4 __attribute__((ext_vector_type(4)));

// Inline-asm 16B global load: cannot be sunk/rewritten by regalloc; dest
// stays live from issue to use, HW latency overlaps following code.
// Matching wait: explicit s_waitcnt vmcnt(0) + sched_barrier(0) (rule #18).
#define GLOAD16(dst, addr) \
    asm volatile("global_load_dwordx4 %0, %1, off" : "=v"(dst) : "v"(addr) : "memory")

// ===========================================================================
// CSR build (once per call — edge topology is layer-invariant)
// ===========================================================================
__global__ __launch_bounds__(256) void hist_kernel(
    const int* __restrict__ dst, int* __restrict__ deg)
{
    int e = blockIdx.x * 256 + threadIdx.x;
    if (e < NEDGES) atomicAdd(&deg[dst[e]], 1);
}

__global__ __launch_bounds__(256) void scan_sum(
    const int* __restrict__ deg, int* __restrict__ partial)
{
    __shared__ int red[256];
    int base = blockIdx.x * 1024;
    int s = 0;
    for (int i = threadIdx.x; i < 1024; i += 256) {
        int idx = base + i;
        if (idx < NNODES) s += deg[idx];
    }
    red[threadIdx.x] = s;
    __syncthreads();
    for (int off = 128; off > 0; off >>= 1) {
        if (threadIdx.x < off) red[threadIdx.x] += red[threadIdx.x + off];
        __syncthreads();
    }
    if (threadIdx.x == 0) partial[blockIdx.x] = red[0];
}

__global__ void scan_part(int* __restrict__ partial, int n, int* __restrict__ rowptr_last)
{
    if (threadIdx.x == 0) {
        int acc = 0;
        for (int i = 0; i < n; i++) { int v = partial[i]; partial[i] = acc; acc += v; }
        rowptr_last[0] = acc;
    }
}

__global__ __launch_bounds__(256) void scan_write(
    const int* __restrict__ deg, const int* __restrict__ partial,
    int* __restrict__ row_ptr)
{
    __shared__ int red[256];
    int base = blockIdx.x * 1024;
    int t = threadIdx.x;
    int v[4];
    int s = 0;
    #pragma unroll
    for (int j = 0; j < 4; j++) {
        int idx = base + t * 4 + j;
        v[j] = (idx < NNODES) ? deg[idx] : 0;
        s += v[j];
    }
    red[t] = s;
    __syncthreads();
    for (int off = 1; off < 256; off <<= 1) {
        int x = (t >= off) ? red[t - off] : 0;
        __syncthreads();
        red[t] += x;
        __syncthreads();
    }
    int ex = red[t] - s + partial[blockIdx.x];
    #pragma unroll
    for (int j = 0; j < 4; j++) {
        int idx = base + t * 4 + j;
        if (idx < NNODES) row_ptr[idx] = ex;
        ex += v[j];
    }
}

__global__ __launch_bounds__(256) void scatter_kernel(
    const int* __restrict__ src, const int* __restrict__ dst,
    const int* __restrict__ eattr, const int* __restrict__ row_ptr,
    int* __restrict__ cursor, int2* __restrict__ epack)
{
    int e = blockIdx.x * 256 + threadIdx.x;
    if (e >= NEDGES) return;
    int d = dst[e];
    int pos = row_ptr[d] + atomicAdd(&cursor[d], 1);
    int a0 = eattr[e * 3 + 0];
    int a1 = eattr[e * 3 + 1];
    int a2 = eattr[e * 3 + 2];
    epack[pos] = make_int2(src[e], a0 * 12 + a1 * 2 + a2);   // combo id 0..59
}

// ===========================================================================
// Weight pre-split (once): W -> transposed [n][k] bf16 hi/lo planes
// ===========================================================================
__global__ __launch_bounds__(256) void wsplit_kernel(
    const float* __restrict__ W1, const float* __restrict__ W2,
    __bf16* __restrict__ bt1h, __bf16* __restrict__ bt1l,
    __bf16* __restrict__ bt2h, __bf16* __restrict__ bt2l)
{
    int gid = blockIdx.x * 256 + threadIdx.x;
    const int total1 = NLAYERS * DIM * HID;
    if (gid < total1) {
        int n = gid % HID; int k = (gid / HID) % DIM; int l = gid / (DIM * HID);
        float w = W1[gid];
        __bf16 hi = (__bf16)w;
        int o = (l * HID + n) * DIM + k;
        bt1h[o] = hi; bt1l[o] = (__bf16)(w - (float)hi);
    } else {
        int g = gid - total1;
        if (g < NLAYERS * HID * DIM) {
            int n = g % DIM; int k = (g / DIM) % HID; int l = g / (HID * DIM);
            float w = W2[g];
            __bf16 hi = (__bf16)w;
            int o = (l * DIM + n) * HID + k;
            bt2h[o] = hi; bt2l[o] = (__bf16)(w - (float)hi);
        }
    }
}

// ===========================================================================
// Aggregation + GIN combine (CSR, zero atomics).  (round-4 structure:
//   4-deep edge pipeline; TRANS=1 gathers from bf16 plane y2b)
// ===========================================================================
template<int TRANS>
__global__ __launch_bounds__(1024) void agg_combine(
    const float* __restrict__ hin,
    const __bf16* __restrict__ hb,
    const int* __restrict__ row_ptr, const int2* __restrict__ epack,
    const float* __restrict__ bond,
    const float* __restrict__ epsv, int lidx,
    const float* __restrict__ csIn, const float* __restrict__ cqIn,
    const float* __restrict__ gamma, const float* __restrict__ beta,
    __bf16* __restrict__ zH, __bf16* __restrict__ zL,
    float* __restrict__ statsZero)
{
    __shared__ float T[BONDSZ * DIM];
    __shared__ float TC[NCOMBO * DIM];
    __shared__ float scs[DIM], shs[DIM];

    for (int i = threadIdx.x; i < BONDSZ * DIM; i += 1024) T[i] = bond[i];
    if (TRANS && threadIdx.x < DIM) {
        int c = threadIdx.x;
        float mu = csIn[c] * INVN;
        float var = cqIn[c] * INVN - mu * mu;
        float sv = gamma[c] * rsqrtf(var + BN_EPS);
        scs[c] = sv; shs[c] = beta[c] - mu * sv;
    }
    if (blockIdx.x == 0 && threadIdx.x < 768) statsZero[threadIdx.x] = 0.f;
    __syncthreads();
    // build combined table: TC[cb] = T[a0] + T[5+a1] + T[11+a2]
    for (int i = threadIdx.x; i < NCOMBO * DIM; i += 1024) {
        int cb = i >> 7, c = i & 127;
        int a0 = cb / 12, r = cb - a0 * 12;
        TC[i] = T[a0 * DIM + c] + T[(5 + (r >> 1)) * DIM + c] + T[(11 + (r & 1)) * DIM + c];
    }
    __syncthreads();

    const int wv = threadIdx.x >> 6;            // 0..15
    const int half = (threadIdx.x >> 5) & 1;
    const int li = threadIdx.x & 31;
    const int node = blockIdx.x * 32 + wv * 2 + half;
    if (node >= NNODES) return;
    const int f = li * 4;

    float4 sc4 = make_float4(1.f, 1.f, 1.f, 1.f);
    float4 sh4 = make_float4(0.f, 0.f, 0.f, 0.f);
    if (TRANS) { sc4 = *(const float4*)&scs[f]; sh4 = *(const float4*)&shs[f]; }

    float ax = 0.f, ay = 0.f, az = 0.f, aw = 0.f;
    const int s = row_ptr[node];
    const int e2 = row_ptr[node + 1];
    int i = s;
    // ---- 4-deep pipelined main loop
    for (; i + 3 < e2; i += 4) {
        int2 ev[4];
        ev[0] = epack[i];     ev[1] = epack[i + 1];
        ev[2] = epack[i + 2]; ev[3] = epack[i + 3];
        float4 gv[4], tv[4];
        #pragma unroll
        for (int u = 0; u < 4; u++) {
            if (TRANS) {
                bf16x4v gb = *(const bf16x4v*)&hb[(size_t)ev[u].x * DIM + f];
                gv[u] = make_float4((float)gb[0], (float)gb[1], (float)gb[2], (float)gb[3]);
            } else {
                gv[u] = *(const float4*)&hin[(size_t)ev[u].x * DIM + f];
            }
            tv[u] = *(const float4*)&TC[ev[u].y * DIM + f];
        }
        #pragma unroll
        for (int u = 0; u < 4; u++) {
            float4 g = gv[u], t = tv[u];
            if (TRANS) {
                g.x = fmaxf(g.x * sc4.x + sh4.x, 0.f); g.y = fmaxf(g.y * sc4.y + sh4.y, 0.f);
                g.z = fmaxf(g.z * sc4.z + sh4.z, 0.f); g.w = fmaxf(g.w * sc4.w + sh4.w, 0.f);
            }
            ax += fmaxf(g.x + t.x, 0.f);
            ay += fmaxf(g.y + t.y, 0.f);
            az += fmaxf(g.z + t.z, 0.f);
            aw += fmaxf(g.w + t.w, 0.f);
        }
    }
    // ---- tail (<=3 edges)
    for (; i < e2; i++) {
        int2 ev = epack[i];
        float4 g;
        if (TRANS) {
            bf16x4v gb = *(const bf16x4v*)&hb[(size_t)ev.x * DIM + f];
            g = make_float4((float)gb[0], (float)gb[1], (float)gb[2], (float)gb[3]);
        } else {
            g = *(const float4*)&hin[(size_t)ev.x * DIM + f];
        }
        float4 t = *(const float4*)&TC[ev.y * DIM + f];
        if (TRANS) {
            g.x = fmaxf(g.x * sc4.x + sh4.x, 0.f); g.y = fmaxf(g.y * sc4.y + sh4.y, 0.f);
            g.z = fmaxf(g.z * sc4.z + sh4.z, 0.f); g.w = fmaxf(g.w * sc4.w + sh4.w, 0.f);
        }
        ax += fmaxf(g.x + t.x, 0.f);
        ay += fmaxf(g.y + t.y, 0.f);
        az += fmaxf(g.z + t.z, 0.f);
        aw += fmaxf(g.w + t.w, 0.f);
    }
    // ---- self term (fp32 exact)
    float4 hv = *(const float4*)&hin[(size_t)node * DIM + f];
    if (TRANS) {
        hv.x = fmaxf(hv.x * sc4.x + sh4.x, 0.f); hv.y = fmaxf(hv.y * sc4.y + sh4.y, 0.f);
        hv.z = fmaxf(hv.z * sc4.z + sh4.z, 0.f); hv.w = fmaxf(hv.w * sc4.w + sh4.w, 0.f);
    }
    float ep = 1.0f + epsv[lidx];
    float z0 = ep * hv.x + ax, z1 = ep * hv.y + ay;
    float z2 = ep * hv.z + az, z3 = ep * hv.w + aw;
    __bf16 h0 = (__bf16)z0, h1 = (__bf16)z1, h2 = (__bf16)z2, h3 = (__bf16)z3;
    size_t o = (size_t)node * DIM + f;
    bf16x4v vh = {h0, h1, h2, h3};
    bf16x4v vl = {(__bf16)(z0 - (float)h0), (__bf16)(z1 - (float)h1),
                  (__bf16)(z2 - (float)h2), (__bf16)(z3 - (float)h3)};
    *(bf16x4v*)(zH + o) = vh;
    *(bf16x4v*)(zL + o) = vl;
}

// ===========================================================================
// Split-precision MFMA GEMM — round-6 skeleton (asm A-burst held across B
// staging; LDS both-plane B; LDS-only K-loop) + two traffic cuts:
//   1) T1 XCD-aware block swizzle: all SWNX column-blocks of a row-stripe
//      get the same bid%8 (= XCD), so the stripe's A is fetched into that
//      XCD's private L2 ONCE. Round-6 counters showed gemm1 FETCH 50.7MB
//      vs A=25.6MB: each XCD re-fetched the stripe (L2s not shared).
//      bid = 8*SWNX*(y/8) + 8*x + (y%8), grid padded to 8*SWNX*ceil(NYB/8).
//   2) y1 stored as bf16 single plane (TRANSFORM=1 A-input): y1 is pre-BN,
//      bf16's 2^-9 relative error ~0.002 sigma after BN. Halves gemm1's
//      write AND gemm2's fetch; A-burst is 8 loads instead of 16.
//   TRANSFORM=0 (gemm1): A = zH/zL planes, writes outB (y1b) only.
//   TRANSFORM=1 (gemm2): A = bf16 y1b; BN+ReLU+split at transform time;
//                        writes outF (y2, for bn_out/agg self) + outB (y2b).
// ===========================================================================
template<int K, int NCOLS, int COLS, int NI, int TRANSFORM, int MINW, int SWNX>
__global__ __launch_bounds__(256, MINW) void gemm_as(
    const __bf16* __restrict__ AH, const __bf16* __restrict__ AL,
    const __bf16* __restrict__ AB,
    const __bf16* __restrict__ BTH, const __bf16* __restrict__ BTL,
    const float* __restrict__ bias,
    const float* __restrict__ csIn, const float* __restrict__ cqIn,
    const float* __restrict__ gamma, const float* __restrict__ beta,
    float* __restrict__ outF, __bf16* __restrict__ outB,
    float* __restrict__ colsum, float* __restrict__ colsumsq)
{
    constexpr int KH  = (K > 128) ? 128 : K;   // staged K per round (32KB LDS)
    constexpr int NH  = K / KH;                // rounds
    constexpr int KCH = KH / 8;                // 16B chunks per col per round
    constexpr int NK  = K / 32;                // total ksteps
    constexpr int NKH = KH / 32;               // ksteps per round
    constexpr int NJ  = COLS / 16;             // col sub-blocks per wave
    constexpr int RB  = NI * 16 * 4;           // rows per block
    constexpr int NYB = MPAD / RB;             // row-stripes

    __shared__ __bf16 sBH[COLS * KH], sBL[COLS * KH];
    __shared__ float redS[COLS], redQ[COLS];
    __shared__ float scs[TRANSFORM ? K : 1], shs[TRANSFORM ? K : 1];

    // ---- XCD swizzle: same-stripe column blocks share bid%8 (same XCD L2)
    const int bid = blockIdx.x;
    const int grp = bid >> 3;
    const int yb  = (grp / SWNX) * 8 + (bid & 7);
    const int xb  = grp % SWNX;
    if (yb >= NYB) return;          // uniform per block: safe before barriers

    const int tid = threadIdx.x;
    const int lane = tid & 63;
    const int wv = tid >> 6;
    const int rowL = lane & 15;
    const int quad = lane >> 4;
    const int n0 = xb * COLS;
    const int r0 = yb * RB + wv * (NI * 16);

    // ---- A burst: ALL per-wave A loads issued via inline asm (held live).
    bf16x8 aH[NI][NK], aL[NI][NK];
    bf16x8 pB[TRANSFORM ? NK : 1];
    #pragma unroll
    for (int i = 0; i < NI; i++) {
        #pragma unroll
        for (int ks = 0; ks < NK; ks++) {
            size_t off = (size_t)(r0 + i * 16 + rowL) * K + ks * 32 + quad * 8;
            if constexpr (!TRANSFORM) {
                GLOAD16(aH[i][ks], AH + off);
                GLOAD16(aL[i][ks], AL + off);
            } else {
                GLOAD16(pB[ks], AB + off);
            }
        }
    }

    if (tid < COLS) { redS[tid] = 0.f; redQ[tid] = 0.f; }
    if (TRANSFORM) {
        for (int c = tid; c < K; c += 256) {
            float mu = csIn[c] * INVN;
            float var = cqIn[c] * INVN - mu * mu;
            float sv = gamma[c] * rsqrtf(var + BN_EPS);
            scs[c] = sv; shs[c] = beta[c] - mu * sv;
        }
    }

    f32x4 acc[NI][NJ] = {};

    #pragma unroll
    for (int h = 0; h < NH; h++) {
        if (h > 0) __syncthreads();   // drain reads before restage
        // ---- stage this K-round of both B planes (swizzled chunk layout)
        #pragma unroll
        for (int it = 0; it < (COLS * KCH) / 256; it++) {
            int c = it * 256 + tid;
            int col = c / KCH, kq = c % KCH;
            int slot = col * KCH + (kq ^ (col & (KCH - 1)));
            size_t g = (size_t)(n0 + col) * K + h * KH + kq * 8;
            bf16x8 vh = *(const bf16x8*)(BTH + g);
            bf16x8 vl = *(const bf16x8*)(BTL + g);
            *(bf16x8*)(sBH + slot * 8) = vh;
            *(bf16x8*)(sBL + slot * 8) = vl;
        }
        __syncthreads();

        if (h == 0) {
            // drain the asm A-burst (overlapped with all of B staging);
            // sched_barrier stops reg-only uses from hoisting above the wait
            asm volatile("s_waitcnt vmcnt(0)" ::: "memory");
            __builtin_amdgcn_sched_barrier(0);
            // ---- one-time A transform (scs/shs valid after the barrier)
            if constexpr (TRANSFORM) {
                #pragma unroll
                for (int ks = 0; ks < NK; ks++) {
                    const int kb = ks * 32 + quad * 8;
                    float4 s0 = *(const float4*)&scs[kb];
                    float4 s1 = *(const float4*)&scs[kb + 4];
                    float4 t0 = *(const float4*)&shs[kb];
                    float4 t1 = *(const float4*)&shs[kb + 4];
                    float sv[8] = {s0.x, s0.y, s0.z, s0.w, s1.x, s1.y, s1.z, s1.w};
                    float tv[8] = {t0.x, t0.y, t0.z, t0.w, t1.x, t1.y, t1.z, t1.w};
                    #pragma unroll
                    for (int e = 0; e < 8; e++) {
                        float v = fmaxf((float)pB[ks][e] * sv[e] + tv[e], 0.f);
                        __bf16 hi = (__bf16)v;
                        aH[0][ks][e] = hi;
                        aL[0][ks][e] = (__bf16)(v - (float)hi);
                    }
                }
            }
        }

        // ---- K-loop for this round: LDS-only reads
        #pragma unroll
        for (int kl = 0; kl < NKH; kl++) {
            const int ks = h * NKH + kl;
            const int kqr = kl * 4 + quad;
            #pragma unroll
            for (int j = 0; j < NJ; j++) {
                int col = j * 16 + rowL;
                int slot = col * KCH + (kqr ^ (col & (KCH - 1)));
                bf16x8 bH = *(const bf16x8*)(sBH + slot * 8);
                bf16x8 bL = *(const bf16x8*)(sBL + slot * 8);
                #pragma unroll
                for (int i = 0; i < NI; i++) {
                    acc[i][j] = __builtin_amdgcn_mfma_f32_16x16x32_bf16(aH[i][ks], bH, acc[i][j], 0, 0, 0);
                    acc[i][j] = __builtin_amdgcn_mfma_f32_16x16x32_bf16(aL[i][ks], bH, acc[i][j], 0, 0, 0);
                    acc[i][j] = __builtin_amdgcn_mfma_f32_16x16x32_bf16(aH[i][ks], bL, acc[i][j], 0, 0, 0);
                }
            }
        }
    }

    // ---- epilogue: bias, bf16 store (+fp32 plane for TRANSFORM), col stats
    #pragma unroll
    for (int j = 0; j < NJ; j++) {
        const int colL = j * 16 + rowL;
        const float bb = bias[n0 + colL];
        float sj = 0.f, qj = 0.f;
        #pragma unroll
        for (int i = 0; i < NI; i++) {
            const int rbase = r0 + i * 16 + quad * 4;
            #pragma unroll
            for (int r = 0; r < 4; r++) {
                const int rr = rbase + r;
                if (rr < NNODES) {
                    float v = acc[i][j][r] + bb;
                    size_t oidx = (size_t)rr * NCOLS + n0 + colL;
                    if constexpr (TRANSFORM) outF[oidx] = v;  // y2 fp32
                    outB[oidx] = (__bf16)v;                   // bf16 plane
                    sj += v;
                    qj += v * v;
                }
            }
        }
        sj += __shfl_xor(sj, 16); sj += __shfl_xor(sj, 32);
        qj += __shfl_xor(qj, 16); qj += __shfl_xor(qj, 32);
        if (quad == 0) {
            atomicAdd(&redS[colL], sj);
            atomicAdd(&redQ[colL], qj);
        }
    }
    __syncthreads();
    if (tid < COLS) {
        atomicAdd(&colsum[n0 + tid], redS[tid]);
        atomicAdd(&colsumsq[n0 + tid], redQ[tid]);
    }
}

// ===========================================================================
// Final outer BN (no relu), scale/shift computed inline from layer-4 stats.
// ===========================================================================
__global__ __launch_bounds__(256) void bn_out(
    const float* __restrict__ y2, const float* __restrict__ csIn,
    const float* __restrict__ cqIn, const float* __restrict__ gamma,
    const float* __restrict__ beta, float* __restrict__ out)
{
    __shared__ float scs[DIM], shs[DIM];
    if (threadIdx.x < DIM) {
        int c = threadIdx.x;
        float mu = csIn[c] * INVN;
        float var = cqIn[c] * INVN - mu * mu;
        float sv = gamma[c] * rsqrtf(var + BN_EPS);
        scs[c] = sv; shs[c] = beta[c] - mu * sv;
    }
    __syncthreads();
    int i = blockIdx.x * 256 + threadIdx.x;
    if (i >= NNODES * 32) return;
    int c = (i & 31) * 4;
    float4 v = *(const float4*)&y2[(size_t)i * 4];
    float4 s = *(const float4*)&scs[c];
    float4 t = *(const float4*)&shs[c];
    v.x = v.x * s.x + t.x;
    v.y = v.y * s.y + t.y;
    v.z = v.z * s.z + t.z;
    v.w = v.w * s.w + t.w;
    *(float4*)&out[(size_t)i * 4] = v;
}

extern "C" void kernel_launch(void* const* d_in, const int* in_sizes, int n_in,
                              void* d_out, int out_size, void* d_ws, size_t ws_size,
                              hipStream_t stream)
{
    const float* x    = (const float*)d_in[0];
    const int*   ei   = (const int*)d_in[1];
    const int*   ea   = (const int*)d_in[2];
    const float* W1   = (const float*)d_in[3];
    const float* b1   = (const float*)d_in[4];
    const float* g1   = (const float*)d_in[5];
    const float* bb1  = (const float*)d_in[6];
    const float* W2   = (const float*)d_in[7];
    const float* b2   = (const float*)d_in[8];
    const float* epsv = (const float*)d_in[9];
    const float* bond = (const float*)d_in[10];
    const float* g2   = (const float*)d_in[11];
    const float* bb2  = (const float*)d_in[12];
    float* out = (float*)d_out;

    const int* src = ei;
    const int* dstp = ei + NEDGES;

    // ---- workspace layout
    float* ws = (float*)d_ws;
    float* y2    = ws;                            // MPAD*DIM fp32
    float* y1F   = y2 + (size_t)MPAD * DIM;       // reused: y1b bf16 plane
    float* stats = y1F + (size_t)MPAD * HID;      // 2 sets x 768
    __bf16* y1b  = (__bf16*)y1F;                  // MPAD*HID bf16 (y1F dead)
    __bf16* zH   = (__bf16*)(stats + 2 * 768);
    __bf16* zL   = zH + (size_t)MPAD * DIM;
    __bf16* bt1h = zL + (size_t)MPAD * DIM;
    __bf16* bt1l = bt1h + (size_t)NLAYERS * DIM * HID;
    __bf16* bt2h = bt1l + (size_t)NLAYERS * DIM * HID;
    __bf16* bt2l = bt2h + (size_t)NLAYERS * HID * DIM;
    int* iws     = (int*)(bt2l + (size_t)NLAYERS * HID * DIM);
    int* deg     = iws;                  // 50000
    int* cursor  = deg + NNODES;         // 50000
    int* row_ptr = cursor + NNODES;      // 50001
    int* partial = row_ptr + NNODES + 1; // 64
    int2* epack  = (int2*)(partial + 64);// 400000 x int2
    __bf16* y2b  = (__bf16*)(((uintptr_t)(epack + NEDGES) + 15) & ~(uintptr_t)15);  // MPAD*DIM bf16

    // ---- build CSR (dst-sorted packed edge list) + split weights, once
    hipMemsetAsync(deg, 0, 2 * NNODES * sizeof(int), stream);
    hist_kernel<<<(NEDGES + 255) / 256, 256, 0, stream>>>(dstp, deg);
    scan_sum<<<NCHUNK, 256, 0, stream>>>(deg, partial);
    scan_part<<<1, 64, 0, stream>>>(partial, NCHUNK, row_ptr + NNODES);
    scan_write<<<NCHUNK, 256, 0, stream>>>(deg, partial, row_ptr);
    scatter_kernel<<<(NEDGES + 255) / 256, 256, 0, stream>>>(
        src, dstp, ea, row_ptr, cursor, epack);
    wsplit_kernel<<<(2 * NLAYERS * DIM * HID + 255) / 256, 256, 0, stream>>>(
        W1, W2, bt1h, bt1l, bt2h, bt2l);

    for (int l = 0; l < NLAYERS; l++) {
        const int p = l & 1;
        float* cs1 = stats + p * 768;
        float* cq1 = cs1 + HID;
        float* cs2 = cq1 + HID;
        float* cq2 = cs2 + DIM;
        float* statsZ = stats + p * 768;   // whole set, zeroed by agg block 0

        if (l == 0) {
            agg_combine<0><<<(NNODES + 31) / 32, 1024, 0, stream>>>(
                x, nullptr, row_ptr, epack, bond + (size_t)l * BONDSZ * DIM,
                epsv, l, nullptr, nullptr, nullptr, nullptr, zH, zL, statsZ);
        } else {
            const int pp = (l - 1) & 1;
            float* pcs2 = stats + pp * 768 + 2 * HID;
            float* pcq2 = pcs2 + DIM;
            agg_combine<1><<<(NNODES + 31) / 32, 1024, 0, stream>>>(
                y2, y2b, row_ptr, epack, bond + (size_t)l * BONDSZ * DIM,
                epsv, l, pcs2, pcq2, g2 + (size_t)(l - 1) * DIM,
                bb2 + (size_t)(l - 1) * DIM, zH, zL, statsZ);
        }

        // gemm1: [MPAD x 128] @ [128 x 256] -> y1b (bf16)
        //   NI=2 (128-row stripes, NYB=391), COLS=64, SWNX=4
        //   grid = 8*4*ceil(391/8) = 1568 (XCD-swizzled, y-guarded)
        gemm_as<DIM, HID, 64, 2, 0, 4, 4><<<1568, 256, 0, stream>>>(
            zH, zL, nullptr,
            bt1h + (size_t)l * HID * DIM, bt1l + (size_t)l * HID * DIM,
            b1 + (size_t)l * HID, nullptr, nullptr, nullptr, nullptr,
            nullptr, y1b, cs1, cq1);

        // gemm2: [MPAD x 256] @ [256 x 128] -> y2 (fp32) + y2b (bf16)
        //   NI=1 (64-row stripes, NYB=782), COLS=64, SWNX=2
        //   grid = 8*2*ceil(782/8) = 1568 (XCD-swizzled, y-guarded)
        gemm_as<HID, DIM, 64, 1, 1, 2, 2><<<1568, 256, 0, stream>>>(
            nullptr, nullptr, y1b,
            bt2h + (size_t)l * DIM * HID, bt2l + (size_t)l * DIM * HID,
            b2 + (size_t)l * DIM, cs1, cq1, g1 + (size_t)l * HID,
            bb1 + (size_t)l * HID, y2, y2b, cs2, cq2);
    }

    // final outer BN (layer 4 -> parity 0), no relu
    {
        float* cs2 = stats + 0 * 768 + 2 * HID;
        float* cq2 = cs2 + DIM;
        bn_out<<<(NNODES * 32 + 255) / 256, 256, 0, stream>>>(
            y2, cs2, cq2, g2 + (size_t)4 * DIM, bb2 + (size_t)4 * DIM, out);
    }
}